// Round 1
// baseline (3359.243 us; speedup 1.0000x reference)
//
#include <hip/hip_runtime.h>
#include <hip/hip_bf16.h>

// MultiHeadedSelfAttention: N=2, S=2048, D=1024, H=16, DH=64, fp32 in/out.
// Round 1 baseline: fp32 vector compute, two kernels.
//   qkv_proj: per-head linear -> Q,K,V in ws, layout [N,H,S,DH], values
//             ROUNDED THROUGH BF16 (accuracy probe for future MFMA path).
//             Q pre-scaled by 1/sqrt(DH).
//   attn:     one wave per 64 queries of one (n,h); lane owns a query;
//             K/V rows via wave-uniform pointers (scalar loads); online softmax.

#define NB 2
#define SS 2048
#define DM 1024
#define NH 16
#define DH 64

__device__ __forceinline__ float bfr(float x) {
    return __bfloat162float(__float2bfloat16(x));
}

__global__ __launch_bounds__(256) void qkv_proj(
    const float* __restrict__ seq,
    const float* __restrict__ Wq, const float* __restrict__ bq,
    const float* __restrict__ Wk, const float* __restrict__ bk,
    const float* __restrict__ Wv, const float* __restrict__ bv,
    float* __restrict__ Q, float* __restrict__ K, float* __restrict__ V)
{
    // one wave per (n, h, s-block of 64); 4 waves per block; 256 blocks total
    const int task = blockIdx.x * 4 + (threadIdx.x >> 6);  // 0..1023
    const int lane = threadIdx.x & 63;
    const int sb = task & 31;          // SS/64 = 32 s-blocks
    const int nh = task >> 5;          // n*NH + h, 0..31
    const int h  = nh & (NH - 1);
    const int s  = sb * 64 + lane;

    // lane's input slice: 64 contiguous floats (head slice of this token)
    const float* xp = seq + ((size_t)(nh >> 4) * SS + s) * DM + h * DH;
    float x[DH];
#pragma unroll
    for (int i = 0; i < DH / 4; ++i) {
        float4 t = ((const float4*)xp)[i];
        x[4*i+0] = t.x; x[4*i+1] = t.y; x[4*i+2] = t.z; x[4*i+3] = t.w;
    }

    const size_t obase = ((size_t)nh * SS + s) * DH;
    const float scale = 0.125f;  // 1/sqrt(64)

    for (int e = 0; e < DH; ++e) {
        // wave-uniform pointers -> scalar loads through constant cache
        const float* wq = Wq + (h * DH + e) * DH;
        const float* wk = Wk + (h * DH + e) * DH;
        const float* wv = Wv + (h * DH + e) * DH;
        float q = bq[h * DH + e];
        float k = bk[h * DH + e];
        float v = bv[h * DH + e];
#pragma unroll
        for (int d = 0; d < DH; ++d) {
            q = fmaf(x[d], wq[d], q);
            k = fmaf(x[d], wk[d], k);
            v = fmaf(x[d], wv[d], v);
        }
        Q[obase + e] = bfr(q * scale);   // pre-scaled
        K[obase + e] = bfr(k);
        V[obase + e] = bfr(v);
    }
}

__global__ __launch_bounds__(64) void attn(
    const float* __restrict__ Q, const float* __restrict__ K,
    const float* __restrict__ V, float* __restrict__ out)
{
    // one wave per block; block handles 64 queries of one (n,h)
    const int task = blockIdx.x;       // 0..1023 = nh*32 + qb
    const int qb = task & 31;
    const int nh = task >> 5;
    const int h  = nh & (NH - 1);
    const int n  = nh >> 4;
    const int lane = threadIdx.x;      // 0..63
    const int sq = qb * 64 + lane;

    const float* qp = Q + ((size_t)nh * SS + sq) * DH;
    float q[DH];
#pragma unroll
    for (int i = 0; i < DH / 4; ++i) {
        float4 t = ((const float4*)qp)[i];
        q[4*i+0] = t.x; q[4*i+1] = t.y; q[4*i+2] = t.z; q[4*i+3] = t.w;
    }

    float m = -1e30f, l = 0.0f;
    float acc[DH];
#pragma unroll
    for (int d = 0; d < DH; ++d) acc[d] = 0.0f;

    const float* kb = K + (size_t)nh * SS * DH;
    const float* vb = V + (size_t)nh * SS * DH;

    for (int j = 0; j < SS; ++j) {
        // wave-uniform row pointers -> scalar loads (broadcast to all lanes)
        const float* kr = kb + j * DH;
        // 4 partial sums to break the fma dependency chain
        float s0 = 0.f, s1 = 0.f, s2 = 0.f, s3 = 0.f;
#pragma unroll
        for (int d = 0; d < DH; d += 4) {
            s0 = fmaf(q[d+0], kr[d+0], s0);
            s1 = fmaf(q[d+1], kr[d+1], s1);
            s2 = fmaf(q[d+2], kr[d+2], s2);
            s3 = fmaf(q[d+3], kr[d+3], s3);
        }
        const float s = (s0 + s1) + (s2 + s3);   // Q pre-scaled, no extra mult

        const float mn = fmaxf(m, s);
        const float p = __expf(s - mn);
        if (mn > m) {                   // running max moved: rescale state
            const float corr = __expf(m - mn);
            l *= corr;
#pragma unroll
            for (int d = 0; d < DH; ++d) acc[d] *= corr;
            m = mn;
        }
        l += p;
        const float pb = bfr(p);        // probe MFMA-grade P precision
        const float* vr = vb + j * DH;
#pragma unroll
        for (int d = 0; d < DH; ++d) acc[d] = fmaf(pb, vr[d], acc[d]);
    }

    const float inv = 1.0f / l;
    float* op = out + (((size_t)n * SS + sq) * NH + h) * DH;
#pragma unroll
    for (int i = 0; i < DH / 4; ++i) {
        float4 t;
        t.x = acc[4*i+0] * inv; t.y = acc[4*i+1] * inv;
        t.z = acc[4*i+2] * inv; t.w = acc[4*i+3] * inv;
        ((float4*)op)[i] = t;
    }
}

extern "C" void kernel_launch(void* const* d_in, const int* in_sizes, int n_in,
                              void* d_out, int out_size, void* d_ws, size_t ws_size,
                              hipStream_t stream) {
    const float* seq = (const float*)d_in[0];
    const float* Wq  = (const float*)d_in[1];
    const float* bq  = (const float*)d_in[2];
    const float* Wk  = (const float*)d_in[3];
    const float* bk  = (const float*)d_in[4];
    const float* Wv  = (const float*)d_in[5];
    const float* bv  = (const float*)d_in[6];
    float* out = (float*)d_out;

    const size_t per = (size_t)NB * NH * SS * DH;  // 4.19M floats = 16.8 MB
    float* Q = (float*)d_ws;
    float* K = Q + per;
    float* V = K + per;

    qkv_proj<<<256, 256, 0, stream>>>(seq, Wq, bq, Wk, bk, Wv, bv, Q, K, V);
    attn<<<1024, 64, 0, stream>>>(Q, K, V, out);
}

// Round 2
// 358.233 us; speedup vs baseline: 9.3772x; 9.3772x over previous
//
#include <hip/hip_runtime.h>
#include <hip/hip_bf16.h>

// MultiHeadedSelfAttention: N=2, S=2048, D=1024, H=16, DH=64, fp32 in/out.
// Round 2: MFMA flash attention.
//   qkv_proj: scalar-broadcast per-head linear, 4096 waves. Writes bf16:
//             Q [nh][s][dh] (pre-scaled by 1/8), K [nh][s][dh], V^T [nh][dh][s].
//   attn:     WG = 4 waves = 128 queries of one (n,h). 64-key KV tiles in LDS
//             (XOR-swizzled 16B chunks). QK^T and PV via mfma_f32_16x16x32_bf16.
//             Online softmax in C-layout; P through LDS (C-layout -> A-layout).

#define NB 2
#define SS 2048
#define DM 1024
#define NH 16
#define DHd 64

typedef __attribute__((ext_vector_type(8))) short bf16x8;   // 8 bf16 = 4 VGPRs
typedef __attribute__((ext_vector_type(4))) float f32x4;

__device__ __forceinline__ unsigned short f2b(float x) {
    __hip_bfloat16 h = __float2bfloat16(x);
    return *reinterpret_cast<unsigned short*>(&h);
}

// element index into a [rows][64] bf16 tile with 16B-chunk XOR swizzle
__device__ __forceinline__ int swz(int row, int chunk) {
    return row * 64 + ((chunk ^ (row & 7)) * 8);
}

__global__ __launch_bounds__(256) void qkv_proj(
    const float* __restrict__ seq,
    const float* __restrict__ Wq, const float* __restrict__ bq,
    const float* __restrict__ Wk, const float* __restrict__ bk,
    const float* __restrict__ Wv, const float* __restrict__ bv,
    unsigned short* __restrict__ Q, unsigned short* __restrict__ K,
    unsigned short* __restrict__ Vt)
{
    // 1024 blocks; block = one (nh, s-block of 64); wave w handles e-chunk w
    const int task = blockIdx.x;
    const int w    = threadIdx.x >> 6;
    const int lane = threadIdx.x & 63;
    const int sb = task & 31;
    const int nh = task >> 5;
    const int h  = nh & (NH - 1);
    const int s  = sb * 64 + lane;

    const float* xp = seq + ((size_t)(nh >> 4) * SS + s) * DM + h * DHd;
    float x[DHd];
#pragma unroll
    for (int i = 0; i < DHd / 4; ++i) {
        float4 t = ((const float4*)xp)[i];
        x[4*i+0] = t.x; x[4*i+1] = t.y; x[4*i+2] = t.z; x[4*i+3] = t.w;
    }

    const size_t qkbase = ((size_t)nh * SS + s) * DHd;
    const int e0 = w * 16;

    for (int e = e0; e < e0 + 16; ++e) {
        const float* wq = Wq + (h * DHd + e) * DHd;   // wave-uniform -> s_load
        const float* wk = Wk + (h * DHd + e) * DHd;
        const float* wv = Wv + (h * DHd + e) * DHd;
        float q = bq[h * DHd + e];
        float k = bk[h * DHd + e];
        float v = bv[h * DHd + e];
#pragma unroll
        for (int d = 0; d < DHd; ++d) {
            q = fmaf(x[d], wq[d], q);
            k = fmaf(x[d], wk[d], k);
            v = fmaf(x[d], wv[d], v);
        }
        Q[qkbase + e] = f2b(q * 0.125f);              // pre-scaled by 1/sqrt(64)
        K[qkbase + e] = f2b(k);
        Vt[((size_t)nh * DHd + e) * SS + s] = f2b(v); // transposed, coalesced in s
    }
}

__global__ __launch_bounds__(256) void attn(
    const unsigned short* __restrict__ Qg, const unsigned short* __restrict__ Kg,
    const unsigned short* __restrict__ Vg, float* __restrict__ out)
{
    __shared__ unsigned short Kl[64 * 64];      // [key][dh]  swizzled, 8 KB
    __shared__ unsigned short Vl[64 * 64];      // [dh][key]  swizzled, 8 KB
    __shared__ unsigned short Pl[4][32 * 64];   // per-wave [qrow][key] swizzled, 16 KB

    const int tid = threadIdx.x;
    const int wv  = tid >> 6;
    const int L   = tid & 63;
    const int lo  = L & 15;     // MFMA m/n lane index
    const int qd  = L >> 4;     // quad (0..3)

    const int bi   = blockIdx.x;
    const int nh   = bi >> 4;
    const int qblk = bi & 15;
    const int h = nh & (NH - 1);
    const int n = nh >> 4;

    const int q0 = qblk * 128 + wv * 32;        // wave's first query row

    const unsigned short* Qnh = Qg + (size_t)nh * SS * DHd;
    const unsigned short* Knh = Kg + (size_t)nh * SS * DHd;
    const unsigned short* Vnh = Vg + (size_t)nh * DHd * SS;   // [dh][s]

    // Q A-fragments [rt][kt]: A[m=lo+16rt][k=kt*32+qd*8+j]
    bf16x8 qf[2][2];
#pragma unroll
    for (int rt = 0; rt < 2; ++rt)
#pragma unroll
        for (int kt = 0; kt < 2; ++kt)
            qf[rt][kt] = *(const bf16x8*)(Qnh + (size_t)(q0 + rt*16 + lo) * DHd
                                          + kt*32 + qd*8);

    f32x4 oacc[2][4];
#pragma unroll
    for (int rt = 0; rt < 2; ++rt)
#pragma unroll
        for (int c2 = 0; c2 < 4; ++c2)
            oacc[rt][c2] = (f32x4){0.f, 0.f, 0.f, 0.f};

    float mrow[8], lrow[8];                     // [rt*4+reg], row = rt*16+qd*4+reg
#pragma unroll
    for (int i = 0; i < 8; ++i) { mrow[i] = -1e30f; lrow[i] = 0.f; }

    for (int kv0 = 0; kv0 < SS; kv0 += 64) {
        __syncthreads();                        // previous tile fully consumed
        // ---- stage K tile and V^T tile (coalesced 16B, swizzled LDS) ----
#pragma unroll
        for (int i = 0; i < 2; ++i) {
            int idx = tid + i * 256;            // 0..511
            int r  = idx >> 3;                  // key row / dh row
            int ch = idx & 7;                   // 16B chunk
            *(uint4*)&Kl[swz(r, ch)] =
                *(const uint4*)(Knh + (size_t)(kv0 + r) * DHd + ch * 8);
            *(uint4*)&Vl[swz(r, ch)] =
                *(const uint4*)(Vnh + (size_t)r * SS + kv0 + ch * 8);
        }
        __syncthreads();

        // ---- S = Q K^T : C[row=qd*4+reg+16rt][col=key=lo+16ct] ----
        f32x4 sacc[2][4];
#pragma unroll
        for (int rt = 0; rt < 2; ++rt)
#pragma unroll
            for (int ct = 0; ct < 4; ++ct)
                sacc[rt][ct] = (f32x4){0.f, 0.f, 0.f, 0.f};
#pragma unroll
        for (int ct = 0; ct < 4; ++ct) {
            const int key = ct * 16 + lo;
#pragma unroll
            for (int kt = 0; kt < 2; ++kt) {
                bf16x8 kf = *(const bf16x8*)&Kl[swz(key, kt * 4 + qd)];
#pragma unroll
                for (int rt = 0; rt < 2; ++rt)
                    sacc[rt][ct] = __builtin_amdgcn_mfma_f32_16x16x32_bf16(
                        qf[rt][kt], kf, sacc[rt][ct], 0, 0, 0);
            }
        }

        // ---- online softmax; write P (bf16) to wave-private LDS ----
#pragma unroll
        for (int rt = 0; rt < 2; ++rt) {
#pragma unroll
            for (int reg = 0; reg < 4; ++reg) {
                float v = fmaxf(fmaxf(sacc[rt][0][reg], sacc[rt][1][reg]),
                                fmaxf(sacc[rt][2][reg], sacc[rt][3][reg]));
                v = fmaxf(v, __shfl_xor(v, 1, 64));
                v = fmaxf(v, __shfl_xor(v, 2, 64));
                v = fmaxf(v, __shfl_xor(v, 4, 64));
                v = fmaxf(v, __shfl_xor(v, 8, 64));
                const float mo = mrow[rt*4+reg];
                const float mn = fmaxf(mo, v);
                const float corr = __expf(mo - mn);
                mrow[rt*4+reg] = mn;
                const int row = rt * 16 + qd * 4 + reg;
                float rs = 0.f;
#pragma unroll
                for (int ct = 0; ct < 4; ++ct) {
                    const float p = __expf(sacc[rt][ct][reg] - mn);
                    rs += p;
                    const int c = ct * 16 + lo;
                    Pl[wv][row * 64 + (((c >> 3) ^ (row & 7)) * 8) + (c & 7)] = f2b(p);
                }
                rs += __shfl_xor(rs, 1, 64);
                rs += __shfl_xor(rs, 2, 64);
                rs += __shfl_xor(rs, 4, 64);
                rs += __shfl_xor(rs, 8, 64);
                lrow[rt*4+reg] = lrow[rt*4+reg] * corr + rs;
#pragma unroll
                for (int c2 = 0; c2 < 4; ++c2)
                    oacc[rt][c2][reg] *= corr;
            }
        }
        __syncthreads();                        // drain P writes (lgkmcnt)

        // ---- O += P V : A = P[m=lo+16rt][k=key], B = V[k=key][n=dh=lo+16c2] ----
#pragma unroll
        for (int kt2 = 0; kt2 < 2; ++kt2) {
            bf16x8 pf[2];
#pragma unroll
            for (int rt = 0; rt < 2; ++rt)
                pf[rt] = *(const bf16x8*)&Pl[wv][swz(rt * 16 + lo, kt2 * 4 + qd)];
#pragma unroll
            for (int c2 = 0; c2 < 4; ++c2) {
                bf16x8 vf = *(const bf16x8*)&Vl[swz(c2 * 16 + lo, kt2 * 4 + qd)];
#pragma unroll
                for (int rt = 0; rt < 2; ++rt)
                    oacc[rt][c2] = __builtin_amdgcn_mfma_f32_16x16x32_bf16(
                        pf[rt], vf, oacc[rt][c2], 0, 0, 0);
            }
        }
    }

    // ---- epilogue: O / l, scattered fp32 stores (64B contiguous per 16 lanes) ----
#pragma unroll
    for (int rt = 0; rt < 2; ++rt) {
#pragma unroll
        for (int reg = 0; reg < 4; ++reg) {
            const float inv = 1.0f / lrow[rt*4+reg];
            const int s = q0 + rt * 16 + qd * 4 + reg;
            float* op = out + ((size_t)n * SS + s) * DM + h * DHd;
#pragma unroll
            for (int c2 = 0; c2 < 4; ++c2)
                op[c2 * 16 + lo] = oacc[rt][c2][reg] * inv;
        }
    }
}

extern "C" void kernel_launch(void* const* d_in, const int* in_sizes, int n_in,
                              void* d_out, int out_size, void* d_ws, size_t ws_size,
                              hipStream_t stream) {
    const float* seq = (const float*)d_in[0];
    const float* Wq  = (const float*)d_in[1];
    const float* bq  = (const float*)d_in[2];
    const float* Wk  = (const float*)d_in[3];
    const float* bk  = (const float*)d_in[4];
    const float* Wv  = (const float*)d_in[5];
    const float* bv  = (const float*)d_in[6];
    float* out = (float*)d_out;

    const size_t per = (size_t)NB * NH * SS * DHd;  // 4.19M bf16 = 8.4 MB each
    unsigned short* Q  = (unsigned short*)d_ws;
    unsigned short* K  = Q + per;
    unsigned short* Vt = K + per;

    qkv_proj<<<1024, 256, 0, stream>>>(seq, Wq, bq, Wk, bk, Wv, bv, Q, K, Vt);
    attn<<<512, 256, 0, stream>>>(Q, K, Vt, out);
}

// Round 3
// 157.197 us; speedup vs baseline: 21.3697x; 2.2789x over previous
//
#include <hip/hip_runtime.h>
#include <hip/hip_bf16.h>

// MultiHeadedSelfAttention: N=2, S=2048, D=1024, H=16, DH=64, fp32 in/out.
// Round 3:
//   qkv_proj: MFMA projection. X-tile (128 s-rows) + Wq/Wk/Wv staged to LDS
//             as bf16. Q,K via transposed form (A=W: C row=e, col=s ->
//             contiguous e-stores to [s][e]); V via direct form (A=X: C row=s,
//             col=e -> contiguous s-stores to V^T [e][s]). Q pre-scaled 1/8.
//   attn:     flash, transposed: S^T = K Q^T (A=K, B=Q). Lane owns a q COLUMN
//             -> softmax reductions are in-register + 2 shfl; P^T regs are 4
//             consecutive keys -> packed b64 writes to P[q][key] (stride 72).
//             O^T = V^T P^T (A=V^T, B=P). Epilogue: contiguous float4 stores.

#define NB 2
#define SS 2048
#define DM 1024
#define NH 16
#define DHd 64

typedef __attribute__((ext_vector_type(8))) short bf16x8;   // 8 bf16 = 4 VGPRs
typedef __attribute__((ext_vector_type(4))) float f32x4;

union U8 { bf16x8 v; unsigned short u[8]; };

__device__ __forceinline__ unsigned short f2b(float x) {
    __hip_bfloat16 h = __float2bfloat16(x);
    return *reinterpret_cast<unsigned short*>(&h);
}

__device__ __forceinline__ bf16x8 pack8(float4 a, float4 b) {
    U8 t;
    t.u[0] = f2b(a.x); t.u[1] = f2b(a.y); t.u[2] = f2b(a.z); t.u[3] = f2b(a.w);
    t.u[4] = f2b(b.x); t.u[5] = f2b(b.y); t.u[6] = f2b(b.z); t.u[7] = f2b(b.w);
    return t.v;
}

// [rows][64] bf16 tile, 16B-chunk XOR swizzle (conflict-free, round-2 verified)
__device__ __forceinline__ int swz(int row, int ch) {
    return row * 64 + ((ch ^ (row & 7)) * 8);
}

__global__ __launch_bounds__(256) void qkv_proj(
    const float* __restrict__ seq,
    const float* __restrict__ Wq, const float* __restrict__ bq,
    const float* __restrict__ Wk, const float* __restrict__ bk,
    const float* __restrict__ Wv, const float* __restrict__ bv,
    unsigned short* __restrict__ Q, unsigned short* __restrict__ K,
    unsigned short* __restrict__ Vt)
{
    __shared__ unsigned short Xl[128 * 64];      // 16 KB
    __shared__ unsigned short Wl[3 * 64 * 64];   // 24 KB

    const int tid = threadIdx.x;
    const int wv = tid >> 6, L = tid & 63, lo = L & 15, qd = L >> 4;
    const int bi = blockIdx.x;
    const int nh = bi >> 4, sb = bi & 15;
    const int h = nh & (NH - 1), n = nh >> 4;
    const int s0 = sb * 128;

    // ---- stage X tile (fp32 -> bf16, swizzled) ----
#pragma unroll
    for (int i = 0; i < 4; ++i) {
        int idx = tid + i * 256;
        int r = idx >> 3, ch = idx & 7;
        const float* src = seq + ((size_t)(n * SS + s0 + r)) * DM + h * DHd + ch * 8;
        float4 a = ((const float4*)src)[0];
        float4 b = ((const float4*)src)[1];
        *(bf16x8*)&Xl[swz(r, ch)] = pack8(a, b);
    }
    // ---- stage Wq, Wk, Wv (fp32 -> bf16, swizzled per matrix) ----
#pragma unroll
    for (int i = 0; i < 6; ++i) {
        int idx = tid + i * 256;
        int mat = idx >> 9;                    // uniform per i (= i>>1)
        int rem = idx & 511;
        int e = rem >> 3, ch = rem & 7;
        const float* Wm = (mat == 0) ? Wq : (mat == 1) ? Wk : Wv;
        const float* src = Wm + (size_t)(h * DHd + e) * DHd + ch * 8;
        float4 a = ((const float4*)src)[0];
        float4 b = ((const float4*)src)[1];
        *(bf16x8*)&Wl[mat * 4096 + swz(e, ch)] = pack8(a, b);
    }
    __syncthreads();

    // X fragments (serve as B for Q/K and A for V): rows wv*32 + st*16 + lo
    bf16x8 xf[2][2];
#pragma unroll
    for (int st = 0; st < 2; ++st)
#pragma unroll
        for (int kt = 0; kt < 2; ++kt)
            xf[st][kt] = *(const bf16x8*)&Xl[swz(wv * 32 + st * 16 + lo, kt * 4 + qd)];

    // ---- Q and K: transposed form. C row = e = et*16+qd*4+reg, col = s ----
#pragma unroll
    for (int m2 = 0; m2 < 2; ++m2) {
        const unsigned short* Wb = &Wl[m2 * 4096];
        const float* bias = m2 ? bk : bq;
        unsigned short* O = m2 ? K : Q;
        const float sc = m2 ? 1.0f : 0.125f;   // Q pre-scaled by 1/sqrt(64)

        f32x4 acc[4][2];
#pragma unroll
        for (int et = 0; et < 4; ++et) {
            float4 bb = *(const float4*)&bias[h * DHd + et * 16 + qd * 4];
#pragma unroll
            for (int st = 0; st < 2; ++st)
                acc[et][st] = (f32x4){bb.x, bb.y, bb.z, bb.w};
        }
#pragma unroll
        for (int et = 0; et < 4; ++et) {
            bf16x8 wf0 = *(const bf16x8*)&Wb[swz(et * 16 + lo, qd)];
            bf16x8 wf1 = *(const bf16x8*)&Wb[swz(et * 16 + lo, 4 + qd)];
#pragma unroll
            for (int st = 0; st < 2; ++st) {
                acc[et][st] = __builtin_amdgcn_mfma_f32_16x16x32_bf16(
                    wf0, xf[st][0], acc[et][st], 0, 0, 0);
                acc[et][st] = __builtin_amdgcn_mfma_f32_16x16x32_bf16(
                    wf1, xf[st][1], acc[et][st], 0, 0, 0);
            }
        }
#pragma unroll
        for (int et = 0; et < 4; ++et)
#pragma unroll
            for (int st = 0; st < 2; ++st) {
                int s = s0 + wv * 32 + st * 16 + lo;
                ushort4 w;
                w.x = f2b(acc[et][st][0] * sc); w.y = f2b(acc[et][st][1] * sc);
                w.z = f2b(acc[et][st][2] * sc); w.w = f2b(acc[et][st][3] * sc);
                *(ushort4*)&O[((size_t)nh * SS + s) * DHd + et * 16 + qd * 4] = w;
            }
    }

    // ---- V: direct form. C row = s = st*16+qd*4+reg, col = e = et*16+lo ----
    {
        const unsigned short* Wb = &Wl[2 * 4096];
        float bvv[4];
#pragma unroll
        for (int et = 0; et < 4; ++et) bvv[et] = bv[h * DHd + et * 16 + lo];

        f32x4 acc[2][4];
#pragma unroll
        for (int st = 0; st < 2; ++st)
#pragma unroll
            for (int et = 0; et < 4; ++et)
                acc[st][et] = (f32x4){bvv[et], bvv[et], bvv[et], bvv[et]};
#pragma unroll
        for (int et = 0; et < 4; ++et) {
            bf16x8 wf0 = *(const bf16x8*)&Wb[swz(et * 16 + lo, qd)];
            bf16x8 wf1 = *(const bf16x8*)&Wb[swz(et * 16 + lo, 4 + qd)];
#pragma unroll
            for (int st = 0; st < 2; ++st) {
                acc[st][et] = __builtin_amdgcn_mfma_f32_16x16x32_bf16(
                    xf[st][0], wf0, acc[st][et], 0, 0, 0);
                acc[st][et] = __builtin_amdgcn_mfma_f32_16x16x32_bf16(
                    xf[st][1], wf1, acc[st][et], 0, 0, 0);
            }
        }
#pragma unroll
        for (int st = 0; st < 2; ++st)
#pragma unroll
            for (int et = 0; et < 4; ++et) {
                int e = et * 16 + lo;
                int s = s0 + wv * 32 + st * 16 + qd * 4;
                ushort4 w;
                w.x = f2b(acc[st][et][0]); w.y = f2b(acc[st][et][1]);
                w.z = f2b(acc[st][et][2]); w.w = f2b(acc[st][et][3]);
                *(ushort4*)&Vt[((size_t)nh * DHd + e) * SS + s] = w;
            }
    }
}

#define PSTR 72   // P row stride (bf16): 16B-aligned b128 reads, bank-minimal

__global__ __launch_bounds__(256) void attn(
    const unsigned short* __restrict__ Qg, const unsigned short* __restrict__ Kg,
    const unsigned short* __restrict__ Vg, float* __restrict__ out)
{
    __shared__ unsigned short Kl[64 * 64];          // [key][dh]  8 KB
    __shared__ unsigned short Vl[64 * 64];          // [dh][key]  8 KB
    __shared__ unsigned short Pl[4][32 * PSTR];     // per-wave [q][key] 18 KB

    const int tid = threadIdx.x;
    const int wv = tid >> 6, L = tid & 63, lo = L & 15, qd = L >> 4;
    const int bi = blockIdx.x;
    const int nh = bi >> 4, qblk = bi & 15;
    const int h = nh & (NH - 1), n = nh >> 4;
    const int q0 = qblk * 128 + wv * 32;

    const unsigned short* Qnh = Qg + (size_t)nh * SS * DHd;
    const unsigned short* Knh = Kg + (size_t)nh * SS * DHd;
    const unsigned short* Vnh = Vg + (size_t)nh * DHd * SS;   // [dh][s]

    // Q as B-operand: B[n=q=ct*16+lo][k=dh=kt*32+qd*8+j]
    bf16x8 qf[2][2];
#pragma unroll
    for (int ct = 0; ct < 2; ++ct)
#pragma unroll
        for (int kt = 0; kt < 2; ++kt)
            qf[ct][kt] = *(const bf16x8*)(Qnh + (size_t)(q0 + ct * 16 + lo) * DHd
                                          + kt * 32 + qd * 8);

    f32x4 oacc[4][2];          // O^T: [dh-tile][q-tile], row=dh, col=q
#pragma unroll
    for (int rt = 0; rt < 4; ++rt)
#pragma unroll
        for (int ct = 0; ct < 2; ++ct)
            oacc[rt][ct] = (f32x4){0.f, 0.f, 0.f, 0.f};

    float m[2] = {-1e30f, -1e30f}, l[2] = {0.f, 0.f};

    for (int kv0 = 0; kv0 < SS; kv0 += 64) {
        __syncthreads();
#pragma unroll
        for (int i = 0; i < 2; ++i) {
            int idx = tid + i * 256;
            int r = idx >> 3, ch = idx & 7;
            *(uint4*)&Kl[swz(r, ch)] =
                *(const uint4*)(Knh + (size_t)(kv0 + r) * DHd + ch * 8);
            *(uint4*)&Vl[swz(r, ch)] =
                *(const uint4*)(Vnh + (size_t)r * SS + kv0 + ch * 8);
        }
        __syncthreads();

        // ---- S^T = K Q^T : C[row=key=rt*16+qd*4+reg][col=q=ct*16+lo] ----
        f32x4 sacc[4][2];
#pragma unroll
        for (int rt = 0; rt < 4; ++rt)
#pragma unroll
            for (int ct = 0; ct < 2; ++ct)
                sacc[rt][ct] = (f32x4){0.f, 0.f, 0.f, 0.f};
#pragma unroll
        for (int rt = 0; rt < 4; ++rt)
#pragma unroll
            for (int kt = 0; kt < 2; ++kt) {
                bf16x8 kf = *(const bf16x8*)&Kl[swz(rt * 16 + lo, kt * 4 + qd)];
#pragma unroll
                for (int ct = 0; ct < 2; ++ct)
                    sacc[rt][ct] = __builtin_amdgcn_mfma_f32_16x16x32_bf16(
                        kf, qf[ct][kt], sacc[rt][ct], 0, 0, 0);
            }

        // ---- online softmax per q-column (in-register + 2 shfl) ----
#pragma unroll
        for (int ct = 0; ct < 2; ++ct) {
            float mx = sacc[0][ct][0];
#pragma unroll
            for (int rt = 0; rt < 4; ++rt)
#pragma unroll
                for (int r = 0; r < 4; ++r)
                    mx = fmaxf(mx, sacc[rt][ct][r]);
            mx = fmaxf(mx, __shfl_xor(mx, 16, 64));
            mx = fmaxf(mx, __shfl_xor(mx, 32, 64));
            const float mo = m[ct];
            const float mn = fmaxf(mo, mx);
            const float corr = __expf(mo - mn);
            float rs = 0.f;
#pragma unroll
            for (int rt = 0; rt < 4; ++rt) {
                float p0 = __expf(sacc[rt][ct][0] - mn);
                float p1 = __expf(sacc[rt][ct][1] - mn);
                float p2 = __expf(sacc[rt][ct][2] - mn);
                float p3 = __expf(sacc[rt][ct][3] - mn);
                rs += (p0 + p1) + (p2 + p3);
                ushort4 w;
                w.x = f2b(p0); w.y = f2b(p1); w.z = f2b(p2); w.w = f2b(p3);
                // P[q=ct*16+lo][key=rt*16+qd*4 .. +3], packed b64
                *(ushort4*)&Pl[wv][(ct * 16 + lo) * PSTR + rt * 16 + qd * 4] = w;
            }
            rs += __shfl_xor(rs, 16, 64);
            rs += __shfl_xor(rs, 32, 64);
            l[ct] = l[ct] * corr + rs;
            m[ct] = mn;
#pragma unroll
            for (int rt = 0; rt < 4; ++rt)
#pragma unroll
                for (int r = 0; r < 4; ++r)
                    oacc[rt][ct][r] *= corr;
        }

        // ---- O^T += V^T P^T : A=V^T[dh][key], B=P[q][key] ----
#pragma unroll
        for (int kt = 0; kt < 2; ++kt) {
            bf16x8 pf[2];
#pragma unroll
            for (int ct = 0; ct < 2; ++ct)
                pf[ct] = *(const bf16x8*)&Pl[wv][(ct * 16 + lo) * PSTR
                                                 + kt * 32 + qd * 8];
#pragma unroll
            for (int rt = 0; rt < 4; ++rt) {
                bf16x8 vf = *(const bf16x8*)&Vl[swz(rt * 16 + lo, kt * 4 + qd)];
#pragma unroll
                for (int ct = 0; ct < 2; ++ct)
                    oacc[rt][ct] = __builtin_amdgcn_mfma_f32_16x16x32_bf16(
                        vf, pf[ct], oacc[rt][ct], 0, 0, 0);
            }
        }
    }

    // ---- epilogue: lane holds O^T[dh=rt*16+qd*4+reg][q=ct*16+lo] ----
#pragma unroll
    for (int ct = 0; ct < 2; ++ct) {
        const float inv = 1.0f / l[ct];
        const int s = q0 + ct * 16 + lo;
#pragma unroll
        for (int rt = 0; rt < 4; ++rt) {
            float4 o;
            o.x = oacc[rt][ct][0] * inv; o.y = oacc[rt][ct][1] * inv;
            o.z = oacc[rt][ct][2] * inv; o.w = oacc[rt][ct][3] * inv;
            *(float4*)&out[((size_t)n * SS + s) * DM + h * DHd
                           + rt * 16 + qd * 4] = o;
        }
    }
}

extern "C" void kernel_launch(void* const* d_in, const int* in_sizes, int n_in,
                              void* d_out, int out_size, void* d_ws, size_t ws_size,
                              hipStream_t stream) {
    const float* seq = (const float*)d_in[0];
    const float* Wq  = (const float*)d_in[1];
    const float* bq  = (const float*)d_in[2];
    const float* Wk  = (const float*)d_in[3];
    const float* bk  = (const float*)d_in[4];
    const float* Wv  = (const float*)d_in[5];
    const float* bv  = (const float*)d_in[6];
    float* out = (float*)d_out;

    const size_t per = (size_t)NB * NH * SS * DHd;  // 4.19M bf16 = 8.4 MB each
    unsigned short* Q  = (unsigned short*)d_ws;
    unsigned short* K  = Q + per;
    unsigned short* Vt = K + per;

    qkv_proj<<<512, 256, 0, stream>>>(seq, Wq, bq, Wk, bk, Wv, bv, Q, K, Vt);
    attn<<<512, 256, 0, stream>>>(Q, K, Vt, out);
}